// Round 2
// baseline (172.365 us; speedup 1.0000x reference)
//
#include <hip/hip_runtime.h>
#include <math.h>

#define L_SEQ 2048
#define DMODEL 1024
#define HEADS 16
#define HD 64
#define BATCH 2
#define MROWS (BATCH*L_SEQ)   // 4096
#define KDIM 1024
#define VSTRIDE 2136          // v^T row stride (shorts): 64 front pad + 2048 + 24 tail

typedef short bfrag8 __attribute__((ext_vector_type(8)));   // 8 bf16 = 4 VGPRs
typedef float f32x4f __attribute__((ext_vector_type(4)));

__device__ __forceinline__ unsigned short f2bf(float f) {
    unsigned u = __float_as_uint(f);
    unsigned r = u + 0x7FFFu + ((u >> 16) & 1u);   // RNE
    return (unsigned short)(r >> 16);
}
__device__ __forceinline__ float bf2f(unsigned short h) {
    return __uint_as_float(((unsigned)h) << 16);
}

// ---------------- fp32 -> bf16 convert (x + 4 weights) + zero kmean_acc ------
__global__ __launch_bounds__(256) void convert_bf16(
    const float* __restrict__ x, const float* __restrict__ wq,
    const float* __restrict__ wk, const float* __restrict__ wv,
    const float* __restrict__ wo,
    unsigned short* __restrict__ xb, unsigned short* __restrict__ qwb,
    unsigned short* __restrict__ kwb, unsigned short* __restrict__ vwb,
    unsigned short* __restrict__ owb, float* __restrict__ kmean_acc)
{
    const int bid = blockIdx.x;
    if (bid == 8192) {
        float4 z = make_float4(0.f, 0.f, 0.f, 0.f);
        *(float4*)&kmean_acc[threadIdx.x * 8]     = z;
        *(float4*)&kmean_acc[threadIdx.x * 8 + 4] = z;
        return;
    }
    const float* src; unsigned short* dst; size_t base;
    if (bid < 4096) { src = x; dst = xb; base = (size_t)bid * 1024; }
    else {
        const int r = bid - 4096; const int w = r >> 10; const int off = r & 1023;
        src = (w==0) ? wq : (w==1) ? wk : (w==2) ? wv : wo;
        dst = (w==0) ? qwb : (w==1) ? kwb : (w==2) ? vwb : owb;
        base = (size_t)off * 1024;
    }
    const size_t idx = base + (size_t)threadIdx.x * 4;
    float4 v = *(const float4*)&src[idx];
    ushort4 o;
    o.x = f2bf(v.x); o.y = f2bf(v.y); o.z = f2bf(v.z); o.w = f2bf(v.w);
    *(ushort4*)&dst[idx] = o;
}

// ------------- 256x192 3-phase MFMA QKV GEMM (T2+T3+T4+T5, full fill) -------
// BM=256 BN=192 BK=64: BM*BN = M*N/256 exactly -> grid (16,16)=256 blocks =
// 1/CU full fill; per-CU staged bytes (BM+BN)*K*2B = 896KB is the geometric
// minimum at full fill. W treated as contiguous [3072][1024] (wq/wk/wv are
// adjacent in workspace); epilogue resolves which-matrix per 16-col fragment.
// 8 waves as 4M x 2N (per-wave 64x96). Column frags interleaved (fn=2*nt+wn)
// so read-phase p reads exactly B stage-round p (rows 64p..64p+63).
// Per K-tile: 3 phases {reads, stage rounds, barrier, lgkmcnt(0), 16 MFMA,
// barrier}; stage stream (7 rounds/K-tile): P1: b2(t+1)->nxt; P2: A0,A1,b0
// (t+2)->cur; P3: A2,A3,b1(t+2)->cur. All same-buffer stages land >=1 barrier
// after their region's last reader. Counted vmcnt(6) once per K-tile at P3
// retires exactly tile t+1's 7 rounds (in-order queue: max 13 outstanding).
// Drain vmcnt(0) only at t==NT-2. setprio(1) around MFMA clusters.
#define GBK 64
#define NT16 (KDIM/64)   // 16 K-tiles

__device__ __forceinline__ void sround(short* ldsreg, const unsigned short* greg,
                                       int ktile, int srw, int sgc, int wb)
{
    // one glds instruction per wave: 64 lanes x 16B = wave's 1KB of an 8KB round
    __builtin_amdgcn_global_load_lds(
        (const __attribute__((address_space(1))) void*)(greg + (size_t)srw * KDIM + (ktile << 6) + sgc),
        (__attribute__((address_space(3))) void*)(ldsreg + wb), 16, 0, 0);
}

__global__ __launch_bounds__(512, 2) void mfma_gemm_qkv(
    const unsigned short* __restrict__ A,
    const unsigned short* __restrict__ W,     // contiguous [3072][1024]
    unsigned short* __restrict__ qo, unsigned short* __restrict__ ko,
    unsigned short* __restrict__ vo, float* __restrict__ kmean_acc)
{
    __shared__ short As[2*256*GBK];   // 64 KB  [buf][region(4x64rows)][row][swz k]
    __shared__ short Bs[2*192*GBK];   // 48 KB  [buf][region(3x64rows)][row][swz k]

    const int tid  = threadIdx.x;
    const int wave = tid >> 6, lane = tid & 63;
    const int quad = lane >> 4, lm = lane & 15;
    const int wm = wave >> 1, wn = wave & 1;        // 4M x 2N wave grid

    // XCD-bijective swizzle (nwg=256, %8==0): each XCD chunk = 2 N-tiles x all
    // M-tiles -> 2 B-panels (1.5MB) resident per XCD L2.
    const int raw = blockIdx.x + (blockIdx.y << 4);
    const int swz = ((raw & 7) << 5) + (raw >> 3);
    const int m0  = (swz & 15) * 256;
    const int n0g = (swz >> 4) * 192;

    // staging geometry (pre-swizzled global source, linear LDS dest)
    const int srw = tid >> 3;                       // 0..63 row within round
    const int sgc = (((tid & 7) ^ (srw & 7)) << 3); // swizzled global col
    const int wb  = wave << 9;                      // wave-uniform LDS base

    const unsigned short* Ar0 = A + (size_t)m0 * KDIM;
    const unsigned short* Ar1 = Ar0 + (size_t)64  * KDIM;
    const unsigned short* Ar2 = Ar0 + (size_t)128 * KDIM;
    const unsigned short* Ar3 = Ar0 + (size_t)192 * KDIM;
    const unsigned short* Br0 = W + (size_t)n0g * KDIM;
    const unsigned short* Br1 = Br0 + (size_t)64  * KDIM;
    const unsigned short* Br2 = Br0 + (size_t)128 * KDIM;

    // -------- prologue: tile0 (7 rounds, buf0) then tile1 (6 rounds, buf1) --
    sround(As,          Ar0, 0, srw, sgc, wb);
    sround(As +  4096,  Ar1, 0, srw, sgc, wb);
    sround(Bs,          Br0, 0, srw, sgc, wb);
    sround(As +  8192,  Ar2, 0, srw, sgc, wb);
    sround(As + 12288,  Ar3, 0, srw, sgc, wb);
    sround(Bs +  4096,  Br1, 0, srw, sgc, wb);
    sround(Bs +  8192,  Br2, 0, srw, sgc, wb);
    sround(As + 16384,  Ar0, 1, srw, sgc, wb);
    sround(As + 20480,  Ar1, 1, srw, sgc, wb);
    sround(Bs + 12288,  Br0, 1, srw, sgc, wb);
    sround(As + 24576,  Ar2, 1, srw, sgc, wb);
    sround(As + 28672,  Ar3, 1, srw, sgc, wb);
    sround(Bs + 16384,  Br1, 1, srw, sgc, wb);
    asm volatile("s_waitcnt vmcnt(6)" ::: "memory");   // tile0 fully landed
    __builtin_amdgcn_s_barrier();

    bfrag8 af[4][2], bfp[2][2];
    f32x4f acc[4][6] = {};

    for (int t = 0; t < NT16; ++t) {
        const int cur = t & 1, nxt = cur ^ 1;
        const int ca = cur * 16384;     // As buf base (shorts)
        const int cb = cur * 12288;     // Bs buf base

        // ---- P1: read A (8) + B pair{0,1} (4); stage b2(t+1)->nxt ----
#pragma unroll
        for (int mt = 0; mt < 4; ++mt) {
            const int ar = wm*64 + mt*16 + lm;
            const int ab = ca + ar*64;
            af[mt][0] = *(const bfrag8*)&As[ab + ((quad ^ (ar & 7)) << 3)];
            af[mt][1] = *(const bfrag8*)&As[ab + (((4 + quad) ^ (ar & 7)) << 3)];
        }
#pragma unroll
        for (int j = 0; j < 2; ++j) {
            const int br = (2*(0*2 + j) + wn)*16 + lm;
            const int bb = cb + br*64;
            bfp[j][0] = *(const bfrag8*)&Bs[bb + ((quad ^ (br & 7)) << 3)];
            bfp[j][1] = *(const bfrag8*)&Bs[bb + (((4 + quad) ^ (br & 7)) << 3)];
        }
        if (t + 1 < NT16) sround(Bs + nxt*12288 + 8192, Br2, t+1, srw, sgc, wb);
        asm volatile("s_waitcnt lgkmcnt(8)" ::: "memory");
        __builtin_amdgcn_s_barrier();
        asm volatile("s_waitcnt lgkmcnt(0)" ::: "memory");
        __builtin_amdgcn_s_setprio(1);
#pragma unroll
        for (int mt = 0; mt < 4; ++mt)
#pragma unroll
            for (int j = 0; j < 2; ++j) {
                f32x4f a = acc[mt][j];
                a = __builtin_amdgcn_mfma_f32_16x16x32_bf16(af[mt][0], bfp[j][0], a, 0, 0, 0);
                a = __builtin_amdgcn_mfma_f32_16x16x32_bf16(af[mt][1], bfp[j][1], a, 0, 0, 0);
                acc[mt][j] = a;
            }
        __builtin_amdgcn_s_setprio(0);
        __builtin_amdgcn_s_barrier();

        // ---- P2: read B pair{2,3}; stage A0,A1,b0 (t+2)->cur ----
#pragma unroll
        for (int j = 0; j < 2; ++j) {
            const int br = (2*(1*2 + j) + wn)*16 + lm;
            const int bb = cb + br*64;
            bfp[j][0] = *(const bfrag8*)&Bs[bb + ((quad ^ (br & 7)) << 3)];
            bfp[j][1] = *(const bfrag8*)&Bs[bb + (((4 + quad) ^ (br & 7)) << 3)];
        }
        if (t + 2 < NT16) {
            sround(As + ca,        Ar0, t+2, srw, sgc, wb);
            sround(As + ca + 4096, Ar1, t+2, srw, sgc, wb);
            sround(Bs + cb,        Br0, t+2, srw, sgc, wb);
        }
        __builtin_amdgcn_s_barrier();
        asm volatile("s_waitcnt lgkmcnt(0)" ::: "memory");
        __builtin_amdgcn_s_setprio(1);
#pragma unroll
        for (int mt = 0; mt < 4; ++mt)
#pragma unroll
            for (int j = 0; j < 2; ++j) {
                f32x4f a = acc[mt][2 + j];
                a = __builtin_amdgcn_mfma_f32_16x16x32_bf16(af[mt][0], bfp[j][0], a, 0, 0, 0);
                a = __builtin_amdgcn_mfma_f32_16x16x32_bf16(af[mt][1], bfp[j][1], a, 0, 0, 0);
                acc[mt][2 + j] = a;
            }
        __builtin_amdgcn_s_setprio(0);
        __builtin_amdgcn_s_barrier();

        // ---- P3: read B pair{4,5}; stage A2,A3,b1 (t+2)->cur; vmcnt ----
#pragma unroll
        for (int j = 0; j < 2; ++j) {
            const int br = (2*(2*2 + j) + wn)*16 + lm;
            const int bb = cb + br*64;
            bfp[j][0] = *(const bfrag8*)&Bs[bb + ((quad ^ (br & 7)) << 3)];
            bfp[j][1] = *(const bfrag8*)&Bs[bb + (((4 + quad) ^ (br & 7)) << 3)];
        }
        if (t + 2 < NT16) {
            sround(As + ca +  8192, Ar2, t+2, srw, sgc, wb);
            sround(As + ca + 12288, Ar3, t+2, srw, sgc, wb);
            sround(Bs + cb +  4096, Br1, t+2, srw, sgc, wb);
        }
        __builtin_amdgcn_s_barrier();
        asm volatile("s_waitcnt lgkmcnt(0)" ::: "memory");
        __builtin_amdgcn_s_setprio(1);
#pragma unroll
        for (int mt = 0; mt < 4; ++mt)
#pragma unroll
            for (int j = 0; j < 2; ++j) {
                f32x4f a = acc[mt][4 + j];
                a = __builtin_amdgcn_mfma_f32_16x16x32_bf16(af[mt][0], bfp[j][0], a, 0, 0, 0);
                a = __builtin_amdgcn_mfma_f32_16x16x32_bf16(af[mt][1], bfp[j][1], a, 0, 0, 0);
                acc[mt][4 + j] = a;
            }
        __builtin_amdgcn_s_setprio(0);
        if (t < NT16 - 2)       { asm volatile("s_waitcnt vmcnt(6)" ::: "memory"); }
        else if (t == NT16 - 2) { asm volatile("s_waitcnt vmcnt(0)" ::: "memory"); }
        __builtin_amdgcn_s_barrier();
    }

    // -------- epilogue: C/D layout col=lane&15, row=quad*4+reg --------
    const int bq = m0 >> 11;          // batch uniform per block (256 | 2048)
#pragma unroll
    for (int nt = 0; nt < 6; ++nt) {
        const int fn  = 2*nt + wn;                 // frag col index 0..11
        const int gng = n0g + fn*16 + lm;          // global N in [0,3072)
        const int which = gng >> 10;               // uniform per frag
        const int gn = gng & 1023;
        const int h = gn >> 6, d = gn & 63;
        if (which == 2) {
            // v: transposed padded layout, coalesced ushort4 (4 consecutive l)
#pragma unroll
            for (int mt = 0; mt < 4; ++mt) {
                const int gm0 = m0 + wm*64 + mt*16 + quad*4;
                const int l0  = gm0 & (L_SEQ-1);
                const f32x4f a = acc[mt][nt];
                ushort4 o;
                o.x = f2bf(a[0]); o.y = f2bf(a[1]);
                o.z = f2bf(a[2]); o.w = f2bf(a[3]);
                *(ushort4*)&vo[((size_t)((bq*HEADS + h)*HD + d))*VSTRIDE + 64 + l0] = o;
            }
        } else {
            unsigned short* Cp = (which==0) ? qo : ko;
#pragma unroll
            for (int mt = 0; mt < 4; ++mt) {
                const f32x4f a = acc[mt][nt];
#pragma unroll
                for (int r = 0; r < 4; ++r) {
                    const int gm = m0 + wm*64 + mt*16 + quad*4 + r;
                    const int l = gm & (L_SEQ-1);
                    Cp[(((size_t)(bq*HEADS + h) * L_SEQ) + l) * HD + d] = f2bf(a[r]);
                }
            }
            if (which == 1) {
                float s = 0.f;
#pragma unroll
                for (int mt = 0; mt < 4; ++mt)
#pragma unroll
                    for (int r = 0; r < 4; ++r) s += acc[mt][nt][r];
                atomicAdd(&kmean_acc[(size_t)(bq*HEADS + h)*HD + d], s);
            }
        }
    }
}

// ---------------- out-projection GEMM: 64x128 tiles (M-split for occupancy) --
__global__ void out_proj_gemm(
    const unsigned short* __restrict__ A, const unsigned short* __restrict__ W,
    float* __restrict__ C)
{
    __shared__ short As[64*GBK];    // 8 KB
    __shared__ short Bs[128*GBK];   // 16 KB

    const int tid  = threadIdx.x;
    const int wave = tid >> 6, lane = tid & 63;
    const int m0   = blockIdx.x * 64;
    const int n0   = blockIdx.y * 128;

    const int quad = lane >> 4, lm = lane & 15;
    const int wm = wave >> 1, wn = wave & 1;   // wave tile: 32 rows x 64 cols

    f32x4f acc[2][4] = {};

    const int sea   = wave * 1024 + lane * 8;
    const int srowa = sea >> 6;
    const int sga   = ((((sea & 63) >> 3) ^ (srowa & 7)) << 3);
    const int seb   = wave * 2048 + lane * 8;
    const int srowb = seb >> 6;
    const int sgb   = ((((seb & 63) >> 3) ^ (srowb & 7)) << 3);

    for (int k0 = 0; k0 < KDIM; k0 += GBK) {
        __syncthreads();
        #pragma unroll
        for (int i = 0; i < 2; ++i) {
            const int ebase = wave * 1024 + i * 512;
            const int row = srowa + i * 8;
            __builtin_amdgcn_global_load_lds(
                (const __attribute__((address_space(1))) void*)(A + (size_t)(m0 + row) * KDIM + k0 + sga),
                (__attribute__((address_space(3))) void*)(&As[ebase]), 16, 0, 0);
        }
        #pragma unroll
        for (int i = 0; i < 4; ++i) {
            const int ebase = wave * 2048 + i * 512;
            const int row = srowb + i * 8;
            __builtin_amdgcn_global_load_lds(
                (const __attribute__((address_space(1))) void*)(W + (size_t)(n0 + row) * KDIM + k0 + sgb),
                (__attribute__((address_space(3))) void*)(&Bs[ebase]), 16, 0, 0);
        }
        __syncthreads();

        #pragma unroll
        for (int kk = 0; kk < 2; ++kk) {
            bfrag8 af[2], bf[4];
            #pragma unroll
            for (int t = 0; t < 2; ++t) {
                const int ar = wm*32 + t*16 + lm;
                af[t] = *(const bfrag8*)&As[ar*GBK + (((kk*4 + quad) ^ (ar & 7)) << 3)];
            }
            #pragma unroll
            for (int t = 0; t < 4; ++t) {
                const int br = wn*64 + t*16 + lm;
                bf[t] = *(const bfrag8*)&Bs[br*GBK + (((kk*4 + quad) ^ (br & 7)) << 3)];
            }
            #pragma unroll
            for (int mt = 0; mt < 2; ++mt)
                #pragma unroll
                for (int nt = 0; nt < 4; ++nt)
                    acc[mt][nt] = __builtin_amdgcn_mfma_f32_16x16x32_bf16(
                        af[mt], bf[nt], acc[mt][nt], 0, 0, 0);
        }
    }

    #pragma unroll
    for (int mt = 0; mt < 2; ++mt)
        #pragma unroll
        for (int nt = 0; nt < 4; ++nt) {
            const int gn = n0 + wn*64 + nt*16 + lm;
            #pragma unroll
            for (int r = 0; r < 4; ++r) {
                const int gm = m0 + wm*32 + mt*16 + quad*4 + r;
                C[(size_t)gm * DMODEL + gn] = acc[mt][nt][r];
            }
        }
}

// ---------------- MFMA windowed attention, zero-staging ----------------
#define P_STRIDE 104    // shorts

__global__ __launch_bounds__(256) void attn_kernel(
    const unsigned short* __restrict__ qb, const unsigned short* __restrict__ kb,
    const unsigned short* __restrict__ vt, const float* __restrict__ kmean_acc,
    const float* __restrict__ g_sep, const float* __restrict__ g_align,
    const float* __restrict__ g_coh, unsigned short* __restrict__ out)
{
    __shared__ unsigned short pl[64 * P_STRIDE];

    const int tid = threadIdx.x;
    const int bh = blockIdx.x >> 5;        // 32 q-tiles per (b,h)
    const int qt = blockIdx.x & 31;
    const int q0 = qt * 64;
    const int j0 = q0 - 64;

    const int w = tid >> 6, lane = tid & 63;
    const int quad = lane >> 4, lm = lane & 15;
    const float sep = g_sep[0], align = g_align[0], coh = g_coh[0];

    const unsigned short* kbh = kb + (size_t)bh * L_SEQ * HD;
    const unsigned short* vbh = vt + (size_t)bh * HD * VSTRIDE;

    const unsigned short* qrow =
        qb + ((size_t)bh * L_SEQ + q0 + w*16 + lm) * HD + quad * 8;
    bfrag8 qa0 = *(const bfrag8*)qrow;
    bfrag8 qa1 = *(const bfrag8*)(qrow + 32);

    const float* kmp = kmean_acc + bh * HD + quad * 8;
    float4 km0 = *(const float4*)(kmp);
    float4 km1 = *(const float4*)(kmp + 4);
    float4 km2 = *(const float4*)(kmp + 32);
    float4 km3 = *(const float4*)(kmp + 36);
    float part =
        bf2f((unsigned short)qa0[0])*km0.x + bf2f((unsigned short)qa0[1])*km0.y +
        bf2f((unsigned short)qa0[2])*km0.z + bf2f((unsigned short)qa0[3])*km0.w +
        bf2f((unsigned short)qa0[4])*km1.x + bf2f((unsigned short)qa0[5])*km1.y +
        bf2f((unsigned short)qa0[6])*km1.z + bf2f((unsigned short)qa0[7])*km1.w +
        bf2f((unsigned short)qa1[0])*km2.x + bf2f((unsigned short)qa1[1])*km2.y +
        bf2f((unsigned short)qa1[2])*km2.z + bf2f((unsigned short)qa1[3])*km2.w +
        bf2f((unsigned short)qa1[4])*km3.x + bf2f((unsigned short)qa1[5])*km3.y +
        bf2f((unsigned short)qa1[6])*km3.z + bf2f((unsigned short)qa1[7])*km3.w;
    part *= (1.f / (float)L_SEQ);
    part += __shfl_xor(part, 16, 64);
    part += __shfl_xor(part, 32, 64);

    f32x4f sacc[6];
    #pragma unroll
    for (int t = 0; t < 6; ++t) {
        int kr = j0 + w*16 + t*16 + lm;
        kr = kr < 0 ? 0 : (kr >= L_SEQ ? L_SEQ - 1 : kr);
        const unsigned short* kp = kbh + (size_t)kr * HD + quad * 8;
        bfrag8 b0 = *(const bfrag8*)kp;
        bfrag8 b1 = *(const bfrag8*)(kp + 32);
        f32x4f z = {0.f, 0.f, 0.f, 0.f};
        z = __builtin_amdgcn_mfma_f32_16x16x32_bf16(qa0, b0, z, 0, 0, 0);
        sacc[t] = __builtin_amdgcn_mfma_f32_16x16x32_bf16(qa1, b1, z, 0, 0, 0);
    }

    float rinv[4];
    #pragma unroll
    for (int r = 0; r < 4; ++r) {
        const int row = quad*4 + r;
        const int i   = q0 + w*16 + row;
        const float mean_i = __shfl(part, row, 64) * 0.125f;
        float sc[6]; float mx = -3.0e38f;
        #pragma unroll
        for (int t = 0; t < 6; ++t) {
            const int jabs = j0 + w*16 + t*16 + lm;
            const int dist = i - jabs;
            float s = sacc[t][r] * 0.125f;
            const float sig = 1.f / (1.f + __expf(-s));
            float adj = s * (1.f + align) - sep * sig * sig - coh * fabsf(s - mean_i);
            const bool ok = (dist >= 0) && (dist < 64) && (jabs >= 0);
            sc[t] = ok ? adj : -3.0e38f;
            mx = fmaxf(mx, sc[t]);
        }
        mx = fmaxf(mx, __shfl_xor(mx, 1, 64));
        mx = fmaxf(mx, __shfl_xor(mx, 2, 64));
        mx = fmaxf(mx, __shfl_xor(mx, 4, 64));
        mx = fmaxf(mx, __shfl_xor(mx, 8, 64));
        float ls = 0.f;
        #pragma unroll
        for (int t = 0; t < 6; ++t) {
            const float p = __expf(sc[t] - mx);   // masked -> 0
            ls += p;
            pl[(w*16 + row) * P_STRIDE + t*16 + lm] = f2bf(p);
        }
        ls += __shfl_xor(ls, 1, 64);
        ls += __shfl_xor(ls, 2, 64);
        ls += __shfl_xor(ls, 4, 64);
        ls += __shfl_xor(ls, 8, 64);
        rinv[r] = 1.f / ls;
    }

    f32x4f oacc[4] = {};
    #pragma unroll
    for (int kk = 0; kk < 3; ++kk) {
        bfrag8 pa = *(const bfrag8*)&pl[(w*16 + lm) * P_STRIDE + kk*32 + quad*8];
        const int loff = 64 + j0 + w*16 + kk*32 + quad*8;
        #pragma unroll
        for (int nt = 0; nt < 4; ++nt) {
            bfrag8 bv = *(const bfrag8*)&vbh[(size_t)(nt*16 + lm) * VSTRIDE + loff];
            oacc[nt] = __builtin_amdgcn_mfma_f32_16x16x32_bf16(pa, bv, oacc[nt], 0, 0, 0);
        }
    }

    const int b = bh >> 4, h = bh & (HEADS - 1);
    #pragma unroll
    for (int nt = 0; nt < 4; ++nt)
        #pragma unroll
        for (int r = 0; r < 4; ++r) {
            const int i = q0 + w*16 + quad*4 + r;
            const int d = nt*16 + lm;
            out[((size_t)(b * L_SEQ + i)) * DMODEL + h * HD + d] =
                f2bf(oacc[nt][r] * rinv[r]);
        }
}

extern "C" void kernel_launch(void* const* d_in, const int* in_sizes, int n_in,
                              void* d_out, int out_size, void* d_ws, size_t ws_size,
                              hipStream_t stream)
{
    (void)in_sizes; (void)n_in; (void)out_size; (void)ws_size;
    const float* x     = (const float*)d_in[0];
    const float* Wq    = (const float*)d_in[1];
    const float* Wk    = (const float*)d_in[2];
    const float* Wv    = (const float*)d_in[3];
    const float* Wo    = (const float*)d_in[4];
    const float* g_sep   = (const float*)d_in[5];
    const float* g_align = (const float*)d_in[6];
    const float* g_coh   = (const float*)d_in[7];
    float* out = (float*)d_out;

    // workspace layout (~49 MB)
    float* kmean_ws = (float*)d_ws;                   // 2048 floats (sum, not mean)
    unsigned short* xb  = (unsigned short*)(kmean_ws + 2048);
    const size_t per = (size_t)MROWS * DMODEL;        // 4 Mi
    unsigned short* wqb = xb  + per;
    unsigned short* wkb = wqb + (size_t)DMODEL*KDIM;  // contiguous after wqb
    unsigned short* wvb = wkb + (size_t)DMODEL*KDIM;  // contiguous after wkb
    unsigned short* wob = wvb + (size_t)DMODEL*KDIM;
    unsigned short* qb  = wob + (size_t)DMODEL*KDIM;
    unsigned short* kb  = qb  + per;
    unsigned short* vtb = kb  + per;                  // [b,h,d,*] padded: 2048*VSTRIDE
    unsigned short* attb = vtb + (size_t)BATCH*HEADS*HD*VSTRIDE;

    convert_bf16<<<dim3(8193), dim3(256), 0, stream>>>(
        x, Wq, Wk, Wv, Wo, xb, wqb, wkb, wvb, wob, kmean_ws);
    mfma_gemm_qkv<<<dim3(16, 16), dim3(512), 0, stream>>>(
        xb, wqb, qb, kb, vtb, kmean_ws);
    attn_kernel<<<dim3(BATCH*HEADS*(L_SEQ/64)), dim3(256), 0, stream>>>(
        qb, kb, vtb, kmean_ws, g_sep, g_align, g_coh, attb);
    out_proj_gemm<<<dim3(MROWS/64, DMODEL/128), dim3(256), 0, stream>>>(
        attb, wob, out);
}

// Round 4
// 147.876 us; speedup vs baseline: 1.1656x; 1.1656x over previous
//
#include <hip/hip_runtime.h>
#include <math.h>

#define L_SEQ 2048
#define DMODEL 1024
#define HEADS 16
#define HD 64
#define BATCH 2
#define MROWS (BATCH*L_SEQ)   // 4096
#define KDIM 1024
#define VSTRIDE 2136          // v^T row stride (shorts): 64 front pad + 2048 + 24 tail

// JOURNAL (rounds 0-3): 8-phase/counted-vmcnt ports of the m201 template
// (256x256 r1: 46us, 256x192 r2: 54.9us) both LOST to this single-buffered
// 128x128 3-blocks/CU structure (43.4us, 594 TF). Ledger/race/swizzle all
// verified correct; per-CU pace stuck at 1.8-2.9 TF/CU vs template's 6.1.
// Family parked. dur_us - qkv_us constant ~117us across rounds => remaining
// controllable budget is qkv + ~30us (convert/attn/out_proj); ~86us looks
// like timed harness fills. R3: container failed (infra) -> resubmit R2 diff
// (convert 8-wide + kmean cross-quad reduce) unchanged for attribution.

typedef short bfrag8 __attribute__((ext_vector_type(8)));   // 8 bf16 = 4 VGPRs
typedef float f32x4f __attribute__((ext_vector_type(4)));
typedef unsigned short ushort8v __attribute__((ext_vector_type(8)));

__device__ __forceinline__ unsigned short f2bf(float f) {
    unsigned u = __float_as_uint(f);
    unsigned r = u + 0x7FFFu + ((u >> 16) & 1u);   // RNE
    return (unsigned short)(r >> 16);
}
__device__ __forceinline__ float bf2f(unsigned short h) {
    return __uint_as_float(((unsigned)h) << 16);
}

// ---------------- fp32 -> bf16 convert (x + 4 weights) + zero kmean_acc ------
// 8 floats/thread: 2x float4 read, 1x 16B vector write (coalescing sweet spot).
// blocks 0..2047: x; 2048..4095: weights (512 blocks each); 4096: zero kmean.
__global__ __launch_bounds__(256) void convert_bf16(
    const float* __restrict__ x, const float* __restrict__ wq,
    const float* __restrict__ wk, const float* __restrict__ wv,
    const float* __restrict__ wo,
    unsigned short* __restrict__ xb, unsigned short* __restrict__ qwb,
    unsigned short* __restrict__ kwb, unsigned short* __restrict__ vwb,
    unsigned short* __restrict__ owb, float* __restrict__ kmean_acc)
{
    const int bid = blockIdx.x;
    if (bid == 4096) {
        float4 z = make_float4(0.f, 0.f, 0.f, 0.f);
        *(float4*)&kmean_acc[threadIdx.x * 8]     = z;
        *(float4*)&kmean_acc[threadIdx.x * 8 + 4] = z;
        return;
    }
    const float* src; unsigned short* dst; size_t base;
    if (bid < 2048) { src = x; dst = xb; base = (size_t)bid * 2048; }
    else {
        const int r = bid - 2048; const int w = r >> 9; const int off = r & 511;
        src = (w==0) ? wq : (w==1) ? wk : (w==2) ? wv : wo;
        dst = (w==0) ? qwb : (w==1) ? kwb : (w==2) ? vwb : owb;
        base = (size_t)off * 2048;
    }
    const size_t idx = base + (size_t)threadIdx.x * 8;
    float4 v0 = *(const float4*)&src[idx];
    float4 v1 = *(const float4*)&src[idx + 4];
    ushort8v o;
    o[0] = f2bf(v0.x); o[1] = f2bf(v0.y); o[2] = f2bf(v0.z); o[3] = f2bf(v0.w);
    o[4] = f2bf(v1.x); o[5] = f2bf(v1.y); o[6] = f2bf(v1.z); o[7] = f2bf(v1.w);
    *(ushort8v*)&dst[idx] = o;
}

// ---------------- MFMA bf16 QKV GEMM: 128x128 tiles (measured optimum) ------
// BK=64, both operands via global_load_lds, XOR-swizzled LDS (k-group cg of
// row r holds global cg ^ (r&7); ds_read unswizzles -> conflict-free b128).
// Staging-bytes floor: Mt=Nt=128 minimizes A*(N/Nt)+B*(M/Mt)=384MB subject to
// grid>=512 and Nt|1024 (r12 falsified smaller tiles: +50% bytes -> +69% time;
// the DMA pipe paces at ~33 GB/s/CU regardless of blocks/CU).
// N=3072 logical over {Wq,Wk,Wv}; q,k -> bf16 head-split [b,h,l,d];
// v -> TRANSPOSED padded [b,h,d,64+l]; k-blocks accumulate kmean_acc.
#define GBK 64

__global__ void mfma_gemm_qkv(
    const unsigned short* __restrict__ A,
    const unsigned short* __restrict__ W0, const unsigned short* __restrict__ W1,
    const unsigned short* __restrict__ W2,
    unsigned short* __restrict__ qo, unsigned short* __restrict__ ko,
    unsigned short* __restrict__ vo, float* __restrict__ kmean_acc)
{
    __shared__ short As[128*GBK];   // [row][kgroup ^ (row&7)] -- swizzled
    __shared__ short Bs[128*GBK];

    const int tid  = threadIdx.x;
    const int wave = tid >> 6, lane = tid & 63;
    const int m0   = blockIdx.x * 128;
    const int n0g  = blockIdx.y * 128;

    const int which = n0g >> 10;                // uniform per block
    const int n0 = n0g & 1023;
    const unsigned short* Wp = (which==0) ? W0 : (which==1) ? W1 : W2;

    const int quad = lane >> 4, lm = lane & 15;
    const int wm = wave >> 1, wn = wave & 1;

    f32x4f acc[4][4] = {};

    // staging geometry: wave stages rows [wave*32, +32), 4 issues x 512 elems
    const int se   = wave * 2048 + lane * 8;
    const int srow = se >> 6;
    const int scg  = (se & 63) >> 3;
    const int sgcol = ((scg ^ (srow & 7)) << 3);

    for (int k0 = 0; k0 < KDIM; k0 += GBK) {
        __syncthreads();
        #pragma unroll
        for (int i = 0; i < 4; ++i) {
            const int ebase = wave * 2048 + i * 512;
            const int row = srow + i * 8;
            __builtin_amdgcn_global_load_lds(
                (const __attribute__((address_space(1))) void*)(A + (size_t)(m0 + row) * KDIM + k0 + sgcol),
                (__attribute__((address_space(3))) void*)(&As[ebase]), 16, 0, 0);
            __builtin_amdgcn_global_load_lds(
                (const __attribute__((address_space(1))) void*)(Wp + (size_t)(n0 + row) * KDIM + k0 + sgcol),
                (__attribute__((address_space(3))) void*)(&Bs[ebase]), 16, 0, 0);
        }
        __syncthreads();

        #pragma unroll
        for (int kk = 0; kk < 2; ++kk) {
            bfrag8 af[4], bf[4];
            #pragma unroll
            for (int t = 0; t < 4; ++t) {
                const int ar = wm*64 + t*16 + lm;
                af[t] = *(const bfrag8*)&As[ar*GBK + (((kk*4 + quad) ^ (ar & 7)) << 3)];
                const int br = wn*64 + t*16 + lm;
                bf[t] = *(const bfrag8*)&Bs[br*GBK + (((kk*4 + quad) ^ (br & 7)) << 3)];
            }
            #pragma unroll
            for (int mt = 0; mt < 4; ++mt)
                #pragma unroll
                for (int nt = 0; nt < 4; ++nt)
                    acc[mt][nt] = __builtin_amdgcn_mfma_f32_16x16x32_bf16(
                        af[mt], bf[nt], acc[mt][nt], 0, 0, 0);
        }
    }

    // epilogue: C/D layout col=lane&15, row=quad*4+reg
    if (which == 2) {
        // v: transposed padded layout, coalesced ushort4 (4 consecutive l)
        #pragma unroll
        for (int mt = 0; mt < 4; ++mt)
            #pragma unroll
            for (int nt = 0; nt < 4; ++nt) {
                const int gn = n0 + wn*64 + nt*16 + lm;
                const int h = gn >> 6, d = gn & 63;
                const int gm0 = m0 + wm*64 + mt*16 + quad*4;
                const int b = gm0 >> 11, l0 = gm0 & (L_SEQ-1);
                ushort4 o;
                o.x = f2bf(acc[mt][nt][0]); o.y = f2bf(acc[mt][nt][1]);
                o.z = f2bf(acc[mt][nt][2]); o.w = f2bf(acc[mt][nt][3]);
                *(ushort4*)&vo[((size_t)((b*HEADS + h)*HD + d))*VSTRIDE + 64 + l0] = o;
            }
    } else {
        unsigned short* Cp = (which==0) ? qo : ko;
        #pragma unroll
        for (int mt = 0; mt < 4; ++mt)
            #pragma unroll
            for (int nt = 0; nt < 4; ++nt) {
                const int gn = n0 + wn*64 + nt*16 + lm;
                const int h = gn >> 6, d = gn & 63;
                #pragma unroll
                for (int r = 0; r < 4; ++r) {
                    const int gm = m0 + wm*64 + mt*16 + quad*4 + r;
                    const int b = gm >> 11, l = gm & (L_SEQ-1);
                    Cp[(((size_t)(b*HEADS + h) * L_SEQ) + l) * HD + d] = f2bf(acc[mt][nt][r]);
                }
            }
        if (which == 1) {
            // kmean: cross-quad shuffle reduce first (cell (h,d) is shared by
            // the 4 quads at fixed lm), then 1 atomic per wave per cell
            // instead of 4 -> 4x fewer same-address atomics.
            const int b = m0 >> 11;
            #pragma unroll
            for (int nt = 0; nt < 4; ++nt) {
                const int gn = n0 + wn*64 + nt*16 + lm;
                const int h = gn >> 6, d = gn & 63;
                float s = 0.f;
                #pragma unroll
                for (int mt = 0; mt < 4; ++mt)
                    #pragma unroll
                    for (int r = 0; r < 4; ++r) s += acc[mt][nt][r];
                s += __shfl_xor(s, 16, 64);
                s += __shfl_xor(s, 32, 64);
                if (quad == 0)
                    atomicAdd(&kmean_acc[(size_t)(b*HEADS + h)*HD + d], s);
            }
        }
    }
}

// ---------------- out-projection GEMM: 64x128 tiles (M-split for occupancy) --
// grid (64,8) = 512 blocks = 2/CU: its staging-bytes floor (192MB) with
// uniform residency. Plain coalesced fp32 writes.
__global__ void out_proj_gemm(
    const unsigned short* __restrict__ A, const unsigned short* __restrict__ W,
    float* __restrict__ C)
{
    __shared__ short As[64*GBK];    // 8 KB
    __shared__ short Bs[128*GBK];   // 16 KB

    const int tid  = threadIdx.x;
    const int wave = tid >> 6, lane = tid & 63;
    const int m0   = blockIdx.x * 64;
    const int n0   = blockIdx.y * 128;

    const int quad = lane >> 4, lm = lane & 15;
    const int wm = wave >> 1, wn = wave & 1;   // wave tile: 32 rows x 64 cols

    f32x4f acc[2][4] = {};

    const int sea   = wave * 1024 + lane * 8;
    const int srowa = sea >> 6;
    const int sga   = ((((sea & 63) >> 3) ^ (srowa & 7)) << 3);
    const int seb   = wave * 2048 + lane * 8;
    const int srowb = seb >> 6;
    const int sgb   = ((((seb & 63) >> 3) ^ (srowb & 7)) << 3);

    for (int k0 = 0; k0 < KDIM; k0 += GBK) {
        __syncthreads();
        #pragma unroll
        for (int i = 0; i < 2; ++i) {
            const int ebase = wave * 1024 + i * 512;
            const int row = srowa + i * 8;
            __builtin_amdgcn_global_load_lds(
                (const __attribute__((address_space(1))) void*)(A + (size_t)(m0 + row) * KDIM + k0 + sga),
                (__attribute__((address_space(3))) void*)(&As[ebase]), 16, 0, 0);
        }
        #pragma unroll
        for (int i = 0; i < 4; ++i) {
            const int ebase = wave * 2048 + i * 512;
            const int row = srowb + i * 8;
            __builtin_amdgcn_global_load_lds(
                (const __attribute__((address_space(1))) void*)(W + (size_t)(n0 + row) * KDIM + k0 + sgb),
                (__attribute__((address_space(3))) void*)(&Bs[ebase]), 16, 0, 0);
        }
        __syncthreads();

        #pragma unroll
        for (int kk = 0; kk < 2; ++kk) {
            bfrag8 af[2], bf[4];
            #pragma unroll
            for (int t = 0; t < 2; ++t) {
                const int ar = wm*32 + t*16 + lm;
                af[t] = *(const bfrag8*)&As[ar*GBK + (((kk*4 + quad) ^ (ar & 7)) << 3)];
            }
            #pragma unroll
            for (int t = 0; t < 4; ++t) {
                const int br = wn*64 + t*16 + lm;
                bf[t] = *(const bfrag8*)&Bs[br*GBK + (((kk*4 + quad) ^ (br & 7)) << 3)];
            }
            #pragma unroll
            for (int mt = 0; mt < 2; ++mt)
                #pragma unroll
                for (int nt = 0; nt < 4; ++nt)
                    acc[mt][nt] = __builtin_amdgcn_mfma_f32_16x16x32_bf16(
                        af[mt], bf[nt], acc[mt][nt], 0, 0, 0);
        }
    }

    #pragma unroll
    for (int mt = 0; mt < 2; ++mt)
        #pragma unroll
        for (int nt = 0; nt < 4; ++nt) {
            const int gn = n0 + wn*64 + nt*16 + lm;
            #pragma unroll
            for (int r = 0; r < 4; ++r) {
                const int gm = m0 + wm*32 + mt*16 + quad*4 + r;
                C[(size_t)gm * DMODEL + gn] = acc[mt][nt][r];
            }
        }
}

// ---------------- MFMA windowed attention, zero-staging ----------------
// Block = one (b,h) x 64 queries; 4 waves x 16 queries. Window base j0 = q0-64,
// 6 QK key-tiles (96 rel slots, all computed; invalid -> masked -> P=0).
// K B-frags and V^T B-frags read DIRECTLY from global (16B aligned by design).
// Only LDS: the P round-trip buffer (per-wave rows -> no barriers at all).
#define P_STRIDE 104    // shorts

__global__ __launch_bounds__(256) void attn_kernel(
    const unsigned short* __restrict__ qb, const unsigned short* __restrict__ kb,
    const unsigned short* __restrict__ vt, const float* __restrict__ kmean_acc,
    const float* __restrict__ g_sep, const float* __restrict__ g_align,
    const float* __restrict__ g_coh, unsigned short* __restrict__ out)
{
    __shared__ unsigned short pl[64 * P_STRIDE];

    const int tid = threadIdx.x;
    const int bh = blockIdx.x >> 5;        // 32 q-tiles per (b,h)
    const int qt = blockIdx.x & 31;
    const int q0 = qt * 64;
    const int j0 = q0 - 64;

    const int w = tid >> 6, lane = tid & 63;
    const int quad = lane >> 4, lm = lane & 15;
    const float sep = g_sep[0], align = g_align[0], coh = g_coh[0];

    const unsigned short* kbh = kb + (size_t)bh * L_SEQ * HD;
    const unsigned short* vbh = vt + (size_t)bh * HD * VSTRIDE;

    // Q a-frags (A[m=lm][k=quad*8+j], ksteps 0/1)
    const unsigned short* qrow =
        qb + ((size_t)bh * L_SEQ + q0 + w*16 + lm) * HD + quad * 8;
    bfrag8 qa0 = *(const bfrag8*)qrow;
    bfrag8 qa1 = *(const bfrag8*)(qrow + 32);

    // q . kmean for the cohesion mean (kmean_acc is a SUM over l; scale here)
    const float* kmp = kmean_acc + bh * HD + quad * 8;
    float4 km0 = *(const float4*)(kmp);
    float4 km1 = *(const float4*)(kmp + 4);
    float4 km2 = *(const float4*)(kmp + 32);
    float4 km3 = *(const float4*)(kmp + 36);
    float part =
        bf2f((unsigned short)qa0[0])*km0.x + bf2f((unsigned short)qa0[1])*km0.y +
        bf2f((unsigned short)qa0[2])*km0.z + bf2f((unsigned short)qa0[3])*km0.w +
        bf2f((unsigned short)qa0[4])*km1.x + bf2f((unsigned short)qa0[5])*km1.y +
        bf2f((unsigned short)qa0[6])*km1.z + bf2f((unsigned short)qa0[7])*km1.w +
        bf2f((unsigned short)qa1[0])*km2.x + bf2f((unsigned short)qa1[1])*km2.y +
        bf2f((unsigned short)qa1[2])*km2.z + bf2f((unsigned short)qa1[3])*km2.w +
        bf2f((unsigned short)qa1[4])*km3.x + bf2f((unsigned short)qa1[5])*km3.y +
        bf2f((unsigned short)qa1[6])*km3.z + bf2f((unsigned short)qa1[7])*km3.w;
    part *= (1.f / (float)L_SEQ);
    part += __shfl_xor(part, 16, 64);
    part += __shfl_xor(part, 32, 64);
    // lane g (0..15) holds q.kmean for query w*16+g (replicated across quads)

    // QK^T: 6 tiles x 2 MFMAs, K rows direct from global (clamped; masked later)
    f32x4f sacc[6];
    #pragma unroll
    for (int t = 0; t < 6; ++t) {
        int kr = j0 + w*16 + t*16 + lm;
        kr = kr < 0 ? 0 : (kr >= L_SEQ ? L_SEQ - 1 : kr);
        const unsigned short* kp = kbh + (size_t)kr * HD + quad * 8;
        bfrag8 b0 = *(const bfrag8*)kp;
        bfrag8 b1 = *(const bfrag8*)(kp + 32);
        f32x4f z = {0.f, 0.f, 0.f, 0.f};
        z = __builtin_amdgcn_mfma_f32_16x16x32_bf16(qa0, b0, z, 0, 0, 0);
        sacc[t] = __builtin_amdgcn_mfma_f32_16x16x32_bf16(qa1, b1, z, 0, 0, 0);
    }

    // Reynolds rules + softmax per row (row = quad*4+r), P -> LDS (per-wave rows)
    float rinv[4];
    #pragma unroll
    for (int r = 0; r < 4; ++r) {
        const int row = quad*4 + r;
        const int i   = q0 + w*16 + row;
        const float mean_i = __shfl(part, row, 64) * 0.125f;
        float sc[6]; float mx = -3.0e38f;
        #pragma unroll
        for (int t = 0; t < 6; ++t) {
            const int jabs = j0 + w*16 + t*16 + lm;
            const int dist = i - jabs;
            float s = sacc[t][r] * 0.125f;
            const float sig = 1.f / (1.f + __expf(-s));
            float adj = s * (1.f + align) - sep * sig * sig - coh * fabsf(s - mean_i);
            const bool ok = (dist >= 0) && (dist < 64) && (jabs >= 0);
            sc[t] = ok ? adj : -3.0e38f;
            mx = fmaxf(mx, sc[t]);
        }
        mx = fmaxf(mx, __shfl_xor(mx, 1, 64));
        mx = fmaxf(mx, __shfl_xor(mx, 2, 64));
        mx = fmaxf(mx, __shfl_xor(mx, 4, 64));
        mx = fmaxf(mx, __shfl_xor(mx, 8, 64));
        float ls = 0.f;
        #pragma unroll
        for (int t = 0; t < 6; ++t) {
            const float p = __expf(sc[t] - mx);   // masked -> 0
            ls += p;
            pl[(w*16 + row) * P_STRIDE + t*16 + lm] = f2bf(p);
        }
        ls += __shfl_xor(ls, 1, 64);
        ls += __shfl_xor(ls, 2, 64);
        ls += __shfl_xor(ls, 4, 64);
        ls += __shfl_xor(ls, 8, 64);
        rinv[r] = 1.f / ls;
    }

    // PV: 3 ksteps x 4 d-tiles; V^T B-frags direct from global (padded rows).
    f32x4f oacc[4] = {};
    #pragma unroll
    for (int kk = 0; kk < 3; ++kk) {
        bfrag8 pa = *(const bfrag8*)&pl[(w*16 + lm) * P_STRIDE + kk*32 + quad*8];
        const int loff = 64 + j0 + w*16 + kk*32 + quad*8;
        #pragma unroll
        for (int nt = 0; nt < 4; ++nt) {
            bfrag8 bv = *(const bfrag8*)&vbh[(size_t)(nt*16 + lm) * VSTRIDE + loff];
            oacc[nt] = __builtin_amdgcn_mfma_f32_16x16x32_bf16(pa, bv, oacc[nt], 0, 0, 0);
        }
    }

    const int b = bh >> 4, h = bh & (HEADS - 1);
    #pragma unroll
    for (int nt = 0; nt < 4; ++nt)
        #pragma unroll
        for (int r = 0; r < 4; ++r) {
            const int i = q0 + w*16 + quad*4 + r;
            const int d = nt*16 + lm;
            out[((size_t)(b * L_SEQ + i)) * DMODEL + h * HD + d] =
                f2bf(oacc[nt][r] * rinv[r]);
        }
}

extern "C" void kernel_launch(void* const* d_in, const int* in_sizes, int n_in,
                              void* d_out, int out_size, void* d_ws, size_t ws_size,
                              hipStream_t stream)
{
    (void)in_sizes; (void)n_in; (void)out_size; (void)ws_size;
    const float* x     = (const float*)d_in[0];
    const float* Wq    = (const float*)d_in[1];
    const float* Wk    = (const float*)d_in[2];
    const float* Wv    = (const float*)d_in[3];
    const float* Wo    = (const float*)d_in[4];
    const float* g_sep   = (const float*)d_in[5];
    const float* g_align = (const float*)d_in[6];
    const float* g_coh   = (const float*)d_in[7];
    float* out = (float*)d_out;

    // workspace layout (~49 MB)
    float* kmean_ws = (float*)d_ws;                   // 2048 floats (sum, not mean)
    unsigned short* xb  = (unsigned short*)(kmean_ws + 2048);
    const size_t per = (size_t)MROWS * DMODEL;        // 4 Mi
    unsigned short* wqb = xb  + per;
    unsigned short* wkb = wqb + (size_t)DMODEL*KDIM;
    unsigned short* wvb = wkb + (size_t)DMODEL*KDIM;
    unsigned short* wob = wvb + (size_t)DMODEL*KDIM;
    unsigned short* qb  = wob + (size_t)DMODEL*KDIM;
    unsigned short* kb  = qb  + per;
    unsigned short* vtb = kb  + per;                  // [b,h,d,*] padded: 2048*VSTRIDE
    unsigned short* attb = vtb + (size_t)BATCH*HEADS*HD*VSTRIDE;

    convert_bf16<<<dim3(4097), dim3(256), 0, stream>>>(
        x, Wq, Wk, Wv, Wo, xb, wqb, wkb, wvb, wob, kmean_ws);
    mfma_gemm_qkv<<<dim3(MROWS/128, 3*DMODEL/128), dim3(256), 0, stream>>>(
        xb, wqb, wkb, wvb, qb, kb, vtb, kmean_ws);
    attn_kernel<<<dim3(BATCH*HEADS*(L_SEQ/64)), dim3(256), 0, stream>>>(
        qb, kb, vtb, kmean_ws, g_sep, g_align, g_coh, attb);
    out_proj_gemm<<<dim3(MROWS/64, DMODEL/128), dim3(256), 0, stream>>>(
        attb, wob, out);
}